// Round 1
// baseline (1088.986 us; speedup 1.0000x reference)
//
#include <hip/hip_runtime.h>
#include <hip/hip_bf16.h>

#define NPTS 600000
#define NKEYS (1 << 22)          // 2 * 128^3 compact key space
#define CHUNK 4096
#define NPART (NKEYS / CHUNK)    // 1024

typedef unsigned int u32;
typedef unsigned short u16;
typedef __attribute__((ext_vector_type(8))) short short8;   // 8 bf16 = 4 VGPRs
typedef __attribute__((ext_vector_type(4))) float f32x4;

__device__ __forceinline__ u16 f2bf(float x) {
  union { float f; u32 u; } c; c.f = x;
  u32 r = c.u + 0x7fffu + ((c.u >> 16) & 1u);   // RNE, inputs finite
  return (u16)(r >> 16);
}

// ---- K0a: fold BN into alpha/beta -------------------------------------------
__global__ void k0a_bn(const float* __restrict__ s, const float* __restrict__ b,
                       const float* __restrict__ m, const float* __restrict__ v,
                       float* __restrict__ ab) {
  int c = threadIdx.x;   // 64 threads
  float a = s[c] * rsqrtf(v[c] + 1e-5f);
  ab[c] = a;
  ab[64 + c] = b[c] - m[c] * a;
}

// ---- K0b: W[27][cin][cout] f32 -> Wt[27][cout][cin] bf16 --------------------
__global__ void k0b_wt(const float* __restrict__ W, u16* __restrict__ Wt) {
  int e = blockIdx.x * 256 + threadIdx.x;
  if (e >= 27 * 4096) return;
  int k = e >> 12, rem = e & 4095, cin = rem >> 6, cout = rem & 63;
  Wt[(k << 12) + (cout << 6) + cin] = f2bf(W[e]);
}

// ---- K1: compact keys + occupancy flags (lut doubles as flags) --------------
__global__ void k1_keys(const int* __restrict__ coords, int* __restrict__ keys,
                        u32* __restrict__ lut) {
  int i = blockIdx.x * 256 + threadIdx.x;
  if (i >= NPTS) return;
  int4 c4 = *(const int4*)(coords + i * 4);
  int k = (c4.w << 21) | ((c4.x >> 1) << 14) | ((c4.y >> 1) << 7) | (c4.z >> 1);
  keys[i] = k;
  lut[k] = 1u;   // benign same-value race
}

// ---- K2a: per-chunk partial sums --------------------------------------------
__global__ void k2a_part(const u32* __restrict__ lut, u32* __restrict__ partials) {
  __shared__ u32 sd[256];
  int blk = blockIdx.x, t = threadIdx.x;
  const u32* p = lut + blk * CHUNK;
  u32 s = 0;
  for (int j = t; j < CHUNK; j += 256) s += p[j];
  sd[t] = s; __syncthreads();
  for (int o = 128; o > 0; o >>= 1) { if (t < o) sd[t] += sd[t + o]; __syncthreads(); }
  if (t == 0) partials[blk] = sd[0];
}

// ---- K2b: scan the 1024 partials (exclusive) + total U ----------------------
__global__ void k2b_top(u32* __restrict__ partials) {
  __shared__ u32 sh[NPART];
  int t = threadIdx.x;   // 1024 threads
  u32 x = partials[t];
  sh[t] = x; __syncthreads();
  for (int off = 1; off < NPART; off <<= 1) {
    u32 add = (t >= off) ? sh[t - off] : 0u;
    __syncthreads();
    sh[t] += add;
    __syncthreads();
  }
  partials[t] = sh[t] - x;                       // exclusive
  if (t == NPART - 1) partials[NPART] = sh[t];   // total unique count U
}

// ---- K2c: fill lut (rank+1 | 0) and rank2key --------------------------------
__global__ void k2c_fill(u32* __restrict__ lut, const u32* __restrict__ partials,
                         int* __restrict__ r2k) {
  __shared__ u32 tsum[256];
  int blk = blockIdx.x, t = threadIdx.x;
  int base = blk * CHUNK + t * 16;
  u32 loc[16]; u32 s = 0;
#pragma unroll
  for (int j = 0; j < 16; j++) { loc[j] = lut[base + j]; s += loc[j]; }
  tsum[t] = s; __syncthreads();
  for (int off = 1; off < 256; off <<= 1) {
    u32 add = (t >= off) ? tsum[t - off] : 0u;
    __syncthreads();
    tsum[t] += add;
    __syncthreads();
  }
  u32 rank = partials[blk] + tsum[t] - s;   // exclusive rank for first elem
#pragma unroll
  for (int j = 0; j < 16; j++) {
    if (loc[j]) { lut[base + j] = rank + 1u; r2k[rank] = base + j; rank++; }
    else lut[base + j] = 0u;
  }
}

// ---- K3: segment-sum feats into d_out (used as f32 fds staging) -------------
__global__ void k3_seg(const float* __restrict__ feats, const int* __restrict__ keys,
                       const u32* __restrict__ lut, float* __restrict__ fds) {
  int idx = blockIdx.x * 256 + threadIdx.x;   // NPTS*16 threads, 4 ch each
  if (idx >= NPTS * 16) return;
  int i = idx >> 4, q = (idx & 15) << 2;
  u32 r = lut[keys[i]] - 1u;
  float4 v = *(const float4*)(feats + (size_t)i * 64 + q);
  float* dst = fds + ((size_t)r << 6) + q;
  atomicAdd(dst + 0, v.x); atomicAdd(dst + 1, v.y);
  atomicAdd(dst + 2, v.z); atomicAdd(dst + 3, v.w);
}

// ---- K3b: fds f32 -> bf16 ---------------------------------------------------
__global__ void k3b_cvt(const float* __restrict__ fds, u16* __restrict__ fb) {
  int idx = blockIdx.x * 256 + threadIdx.x;   // NPTS*16 threads, 4 elems each
  if (idx >= NPTS * 16) return;
  float4 v = *(const float4*)(fds + (size_t)idx * 4);
  ushort4 o;
  o.x = f2bf(v.x); o.y = f2bf(v.y); o.z = f2bf(v.z); o.w = f2bf(v.w);
  *(ushort4*)(fb + (size_t)idx * 4) = o;
}

// ---- K4: gather + MFMA conv + BN/ReLU ---------------------------------------
// block = 256 thr (4 waves); each wave owns 64 output rows (4 row-tiles of 16).
// mfma_f32_16x16x32_bf16: A lane: row=l&15, k=(l>>4)*8..+8 ; B from Wt rows
// (col=l&15, same k slice); D: col=l&15, row=(l>>4)*4+i  [m89/m91 layout].
__global__ __launch_bounds__(256) void k4_conv(
    const u32* __restrict__ lut, const int* __restrict__ r2k,
    const u16* __restrict__ fdsb, const u16* __restrict__ Wt,
    const u32* __restrict__ pU, const float* __restrict__ ab,
    float* __restrict__ out) {
  const u32 U = *pU;
  int tid = threadIdx.x;
  int w = tid >> 6, l = tid & 63;
  int col = l & 15, kg = l >> 4;
  int rbase = blockIdx.x * 256 + w * 64;

  // hoist per-row-tile key decode (lane handles A-row = col of each tile)
  int kk[4], xx[4], yy[4], zz[4];
#pragma unroll
  for (int rt = 0; rt < 4; rt++) {
    int r = rbase + rt * 16 + col;
    int key = ((u32)r < U) ? r2k[r] : -1;
    kk[rt] = key;
    zz[rt] = key & 127; yy[rt] = (key >> 7) & 127; xx[rt] = (key >> 14) & 127;
  }

  f32x4 acc[4][4] = {};   // [row-tile][cout-tile]

  for (int k = 0; k < 27; k++) {
    int dx = k / 9 - 1, dy = (k / 3) % 3 - 1, dz = k % 3 - 1;
    int dkey = dx * 16384 + dy * 128 + dz;
    // B fragments: whole Wt[k] (8KB) split across 2 k-halves x 4 cout-tiles
    short8 bf[2][4];
    const u16* wk = Wt + (k << 12);
#pragma unroll
    for (int h = 0; h < 2; h++)
#pragma unroll
      for (int ct = 0; ct < 4; ct++)
        bf[h][ct] = *(const short8*)(wk + (((ct << 4) + col) << 6) + (h << 5) + (kg << 3));
#pragma unroll
    for (int rt = 0; rt < 4; rt++) {
      int nx = xx[rt] + dx, ny = yy[rt] + dy, nz = zz[rt] + dz;
      bool ok = (kk[rt] >= 0) & ((u32)nx < 128u) & ((u32)ny < 128u) & ((u32)nz < 128u);
      u32 lv = ok ? lut[kk[rt] + dkey] : 0u;
      short8 a0 = {0,0,0,0,0,0,0,0}, a1 = {0,0,0,0,0,0,0,0};
      if (lv) {
        const u16* fr = fdsb + ((size_t)(lv - 1u) << 6) + (kg << 3);
        a0 = *(const short8*)(fr);
        a1 = *(const short8*)(fr + 32);
      }
#pragma unroll
      for (int ct = 0; ct < 4; ct++) {
        acc[rt][ct] = __builtin_amdgcn_mfma_f32_16x16x32_bf16(a0, bf[0][ct], acc[rt][ct], 0, 0, 0);
        acc[rt][ct] = __builtin_amdgcn_mfma_f32_16x16x32_bf16(a1, bf[1][ct], acc[rt][ct], 0, 0, 0);
      }
    }
  }

  // epilogue: BN + ReLU, zeros for invalid (r >= U) rows
  float al[4], be[4];
#pragma unroll
  for (int ct = 0; ct < 4; ct++) { int c = (ct << 4) | col; al[ct] = ab[c]; be[ct] = ab[64 + c]; }
#pragma unroll
  for (int rt = 0; rt < 4; rt++) {
#pragma unroll
    for (int i = 0; i < 4; i++) {
      int r = rbase + rt * 16 + (kg << 2) + i;
      if (r >= NPTS) continue;
      bool valid = ((u32)r < U);
      size_t rb = (size_t)r << 6;
#pragma unroll
      for (int ct = 0; ct < 4; ct++) {
        int c = (ct << 4) | col;
        float vv = 0.f;
        if (valid) {
          vv = fmaf(acc[rt][ct][i], al[ct], be[ct]);
          vv = vv > 0.f ? vv : 0.f;
        }
        out[rb + c] = vv;
      }
    }
  }
}

extern "C" void kernel_launch(void* const* d_in, const int* in_sizes, int n_in,
                              void* d_out, int out_size, void* d_ws, size_t ws_size,
                              hipStream_t stream) {
  const int*   coords = (const int*)d_in[0];
  const float* feats  = (const float*)d_in[1];
  const float* W      = (const float*)d_in[2];
  const float* bns    = (const float*)d_in[3];
  const float* bnb    = (const float*)d_in[4];
  const float* bnm    = (const float*)d_in[5];
  const float* bnv    = (const float*)d_in[6];
  float* out = (float*)d_out;

  char* ws = (char*)d_ws;
  size_t off = 0;
  auto alloc = [&](size_t bytes) -> void* {
    void* p = ws + off;
    off += (bytes + 255) & ~(size_t)255;
    return p;
  };
  u32* lut      = (u32*)alloc((size_t)NKEYS * 4);        // flags, then rank+1|0
  u32* partials = (u32*)alloc((NPART + 8) * 4);
  int* keys     = (int*)alloc((size_t)NPTS * 4);
  int* r2k      = (int*)alloc((size_t)NPTS * 4);
  u16* fdsb     = (u16*)alloc((size_t)NPTS * 64 * 2);
  u16* Wt       = (u16*)alloc((size_t)27 * 4096 * 2);
  float* ab     = (float*)alloc(128 * 4);
  (void)ws_size; (void)out_size; (void)n_in; (void)in_sizes;

  // d_out doubles as the f32 segment-sum staging buffer; zero it + the flags.
  hipMemsetAsync(out, 0, (size_t)NPTS * 64 * 4, stream);
  hipMemsetAsync(lut, 0, (size_t)NKEYS * 4, stream);

  k0a_bn<<<1, 64, 0, stream>>>(bns, bnb, bnm, bnv, ab);
  k0b_wt<<<(27 * 4096 + 255) / 256, 256, 0, stream>>>(W, Wt);
  k1_keys<<<(NPTS + 255) / 256, 256, 0, stream>>>(coords, keys, lut);
  k2a_part<<<NPART, 256, 0, stream>>>(lut, partials);
  k2b_top<<<1, NPART, 0, stream>>>(partials);
  k2c_fill<<<NPART, 256, 0, stream>>>(lut, partials, r2k);
  k3_seg<<<(NPTS * 16 + 255) / 256, 256, 0, stream>>>(feats, keys, lut, out);
  k3b_cvt<<<(NPTS * 16 + 255) / 256, 256, 0, stream>>>(out, fdsb);
  k4_conv<<<(NPTS + 255) / 256, 256, 0, stream>>>(lut, r2k, fdsb, Wt,
                                                  partials + NPART, ab, out);
}

// Round 2
// 636.636 us; speedup vs baseline: 1.7105x; 1.7105x over previous
//
#include <hip/hip_runtime.h>
#include <hip/hip_bf16.h>

#define NPTS 600000
#define NKEYS (1 << 22)          // 2 * 128^3 compact key space
#define CHUNK 4096
#define NPART (NKEYS / CHUNK)    // 1024

typedef unsigned int u32;
typedef unsigned short u16;
typedef __attribute__((ext_vector_type(8))) short short8;   // 8 bf16 = 4 VGPRs
typedef __attribute__((ext_vector_type(4))) float f32x4;

__device__ __forceinline__ u16 f2bf(float x) {
  union { float f; u32 u; } c; c.f = x;
  u32 r = c.u + 0x7fffu + ((c.u >> 16) & 1u);   // RNE, inputs finite
  return (u16)(r >> 16);
}

// ---- K0a: fold BN into alpha/beta -------------------------------------------
__global__ void k0a_bn(const float* __restrict__ s, const float* __restrict__ b,
                       const float* __restrict__ m, const float* __restrict__ v,
                       float* __restrict__ ab) {
  int c = threadIdx.x;   // 64 threads
  float a = s[c] * rsqrtf(v[c] + 1e-5f);
  ab[c] = a;
  ab[64 + c] = b[c] - m[c] * a;
}

// ---- K0b: W[27][cin][cout] f32 -> Wt[27][cout][cin] bf16 --------------------
__global__ void k0b_wt(const float* __restrict__ W, u16* __restrict__ Wt) {
  int e = blockIdx.x * 256 + threadIdx.x;
  if (e >= 27 * 4096) return;
  int k = e >> 12, rem = e & 4095, cin = rem >> 6, cout = rem & 63;
  Wt[(k << 12) + (cout << 6) + cin] = f2bf(W[e]);
}

// ---- K1: compact keys + per-voxel point counts ------------------------------
__global__ void k1_keys(const int* __restrict__ coords, int* __restrict__ keys,
                        u32* __restrict__ lut) {
  int i = blockIdx.x * 256 + threadIdx.x;
  if (i >= NPTS) return;
  int4 c4 = *(const int4*)(coords + i * 4);
  int k = (c4.w << 21) | ((c4.x >> 1) << 14) | ((c4.y >> 1) << 7) | (c4.z >> 1);
  keys[i] = k;
  atomicAdd(&lut[k], 1u);   // count points per voxel (~600k atomics total)
}

// ---- K2a: per-chunk occupied-voxel counts -----------------------------------
__global__ void k2a_part(const u32* __restrict__ lut, u32* __restrict__ partials) {
  __shared__ u32 sd[256];
  int blk = blockIdx.x, t = threadIdx.x;
  const u32* p = lut + blk * CHUNK;
  u32 s = 0;
  for (int j = t; j < CHUNK; j += 256) s += (p[j] != 0u);
  sd[t] = s; __syncthreads();
  for (int o = 128; o > 0; o >>= 1) { if (t < o) sd[t] += sd[t + o]; __syncthreads(); }
  if (t == 0) partials[blk] = sd[0];
}

// ---- K2b: scan the 1024 partials (exclusive) + total U ----------------------
__global__ void k2b_top(u32* __restrict__ partials) {
  __shared__ u32 sh[NPART];
  int t = threadIdx.x;   // 1024 threads
  u32 x = partials[t];
  sh[t] = x; __syncthreads();
  for (int off = 1; off < NPART; off <<= 1) {
    u32 add = (t >= off) ? sh[t - off] : 0u;
    __syncthreads();
    sh[t] += add;
    __syncthreads();
  }
  partials[t] = sh[t] - x;                       // exclusive
  if (t == NPART - 1) partials[NPART] = sh[t];   // total unique count U
}

// ---- K2c: fill lut ((rank+1)|multi<<31 or 0), r2k, zero multi f32 rows ------
__global__ void k2c_fill(u32* __restrict__ lut, const u32* __restrict__ partials,
                         int* __restrict__ r2k, float* __restrict__ fds32) {
  __shared__ u32 tsum[256];
  int blk = blockIdx.x, t = threadIdx.x;
  int base = blk * CHUNK + t * 16;
  u32 loc[16]; u32 s = 0;
#pragma unroll
  for (int j = 0; j < 16; j++) { loc[j] = lut[base + j]; s += (loc[j] != 0u); }
  tsum[t] = s; __syncthreads();
  for (int off = 1; off < 256; off <<= 1) {
    u32 add = (t >= off) ? tsum[t - off] : 0u;
    __syncthreads();
    tsum[t] += add;
    __syncthreads();
  }
  u32 rank = partials[blk] + tsum[t] - s;   // exclusive rank for first elem
#pragma unroll
  for (int j = 0; j < 16; j++) {
    if (loc[j]) {
      u32 flag = (loc[j] > 1u) ? 0x80000000u : 0u;
      lut[base + j] = (rank + 1u) | flag;
      r2k[rank] = base + j;
      if (flag) {   // zero the f32 accumulation row for multi-point voxels
        float4 z = {0.f, 0.f, 0.f, 0.f};
        float* d = fds32 + ((size_t)rank << 6);
#pragma unroll
        for (int c = 0; c < 16; c++) *(float4*)(d + c * 4) = z;
      }
      rank++;
    } else lut[base + j] = 0u;
  }
}

// ---- K3: fused segment-sum: singles -> bf16 direct, multis -> f32 atomics ---
__global__ void k3_seg(const float* __restrict__ feats, const int* __restrict__ keys,
                       const u32* __restrict__ lut, float* __restrict__ fds32,
                       u16* __restrict__ fdsb) {
  int idx = blockIdx.x * 256 + threadIdx.x;   // NPTS*16 threads, 4 ch each
  if (idx >= NPTS * 16) return;
  int i = idx >> 4, q = (idx & 15) << 2;
  u32 lv = lut[keys[i]];
  u32 r = (lv & 0x7fffffffu) - 1u;
  float4 v = *(const float4*)(feats + (size_t)i * 64 + q);
  if (lv >> 31) {               // ~13% of points: shared voxel, accumulate f32
    float* dst = fds32 + ((size_t)r << 6) + q;
    atomicAdd(dst + 0, v.x); atomicAdd(dst + 1, v.y);
    atomicAdd(dst + 2, v.z); atomicAdd(dst + 3, v.w);
  } else {                      // ~87%: sole occupant, convert + plain store
    ushort4 o;
    o.x = f2bf(v.x); o.y = f2bf(v.y); o.z = f2bf(v.z); o.w = f2bf(v.w);
    *(ushort4*)(fdsb + ((size_t)r << 6) + q) = o;
  }
}

// ---- K3b: convert only multi-voxel rows f32 -> bf16 -------------------------
__global__ void k3b_fix(const int* __restrict__ r2k, const u32* __restrict__ lut,
                        const u32* __restrict__ pU,
                        const float* __restrict__ fds32, u16* __restrict__ fdsb) {
  int idx = blockIdx.x * 256 + threadIdx.x;   // NPTS*4 threads, 16 ch each
  int r = idx >> 2;
  if (r >= (int)(*pU)) return;
  u32 lv = lut[r2k[r]];
  if (!(lv >> 31)) return;
  int q = (idx & 3) << 4;
  const float* src = fds32 + ((size_t)r << 6) + q;
  u16* dst = fdsb + ((size_t)r << 6) + q;
#pragma unroll
  for (int j = 0; j < 4; j++) {
    float4 v = *(const float4*)(src + j * 4);
    ushort4 o;
    o.x = f2bf(v.x); o.y = f2bf(v.y); o.z = f2bf(v.z); o.w = f2bf(v.w);
    *(ushort4*)(dst + j * 4) = o;
  }
}

// ---- K4: gather + MFMA conv + BN/ReLU ---------------------------------------
// block = 256 thr (4 waves); each wave owns 64 output rows (4 row-tiles of 16).
// mfma_f32_16x16x32_bf16: A lane: row=l&15, k=(l>>4)*8..+8 ; B from Wt rows
// (col=l&15, same k slice); D: col=l&15, row=(l>>4)*4+i  [m89/m91 layout].
__global__ __launch_bounds__(256) void k4_conv(
    const u32* __restrict__ lut, const int* __restrict__ r2k,
    const u16* __restrict__ fdsb, const u16* __restrict__ Wt,
    const u32* __restrict__ pU, const float* __restrict__ ab,
    float* __restrict__ out) {
  const u32 U = *pU;
  int tid = threadIdx.x;
  int w = tid >> 6, l = tid & 63;
  int col = l & 15, kg = l >> 4;
  int rbase = blockIdx.x * 256 + w * 64;

  // hoist per-row-tile key decode (lane handles A-row = col of each tile)
  int kk[4], xx[4], yy[4], zz[4];
#pragma unroll
  for (int rt = 0; rt < 4; rt++) {
    int r = rbase + rt * 16 + col;
    int key = ((u32)r < U) ? r2k[r] : -1;
    kk[rt] = key;
    zz[rt] = key & 127; yy[rt] = (key >> 7) & 127; xx[rt] = (key >> 14) & 127;
  }

  f32x4 acc[4][4] = {};   // [row-tile][cout-tile]

  for (int k = 0; k < 27; k++) {
    int dx = k / 9 - 1, dy = (k / 3) % 3 - 1, dz = k % 3 - 1;
    int dkey = dx * 16384 + dy * 128 + dz;
    // B fragments: whole Wt[k] (8KB) split across 2 k-halves x 4 cout-tiles
    short8 bf[2][4];
    const u16* wk = Wt + (k << 12);
#pragma unroll
    for (int h = 0; h < 2; h++)
#pragma unroll
      for (int ct = 0; ct < 4; ct++)
        bf[h][ct] = *(const short8*)(wk + (((ct << 4) + col) << 6) + (h << 5) + (kg << 3));
#pragma unroll
    for (int rt = 0; rt < 4; rt++) {
      int nx = xx[rt] + dx, ny = yy[rt] + dy, nz = zz[rt] + dz;
      bool ok = (kk[rt] >= 0) & ((u32)nx < 128u) & ((u32)ny < 128u) & ((u32)nz < 128u);
      u32 lv = ok ? lut[kk[rt] + dkey] : 0u;
      short8 a0 = {0,0,0,0,0,0,0,0}, a1 = {0,0,0,0,0,0,0,0};
      if (lv) {
        const u16* fr = fdsb + ((size_t)((lv & 0x7fffffffu) - 1u) << 6) + (kg << 3);
        a0 = *(const short8*)(fr);
        a1 = *(const short8*)(fr + 32);
      }
#pragma unroll
      for (int ct = 0; ct < 4; ct++) {
        acc[rt][ct] = __builtin_amdgcn_mfma_f32_16x16x32_bf16(a0, bf[0][ct], acc[rt][ct], 0, 0, 0);
        acc[rt][ct] = __builtin_amdgcn_mfma_f32_16x16x32_bf16(a1, bf[1][ct], acc[rt][ct], 0, 0, 0);
      }
    }
  }

  // epilogue: BN + ReLU, zeros for invalid (r >= U) rows
  float al[4], be[4];
#pragma unroll
  for (int ct = 0; ct < 4; ct++) { int c = (ct << 4) | col; al[ct] = ab[c]; be[ct] = ab[64 + c]; }
#pragma unroll
  for (int rt = 0; rt < 4; rt++) {
#pragma unroll
    for (int i = 0; i < 4; i++) {
      int r = rbase + rt * 16 + (kg << 2) + i;
      if (r >= NPTS) continue;
      bool valid = ((u32)r < U);
      size_t rb = (size_t)r << 6;
#pragma unroll
      for (int ct = 0; ct < 4; ct++) {
        int c = (ct << 4) | col;
        float vv = 0.f;
        if (valid) {
          vv = fmaf(acc[rt][ct][i], al[ct], be[ct]);
          vv = vv > 0.f ? vv : 0.f;
        }
        out[rb + c] = vv;
      }
    }
  }
}

extern "C" void kernel_launch(void* const* d_in, const int* in_sizes, int n_in,
                              void* d_out, int out_size, void* d_ws, size_t ws_size,
                              hipStream_t stream) {
  const int*   coords = (const int*)d_in[0];
  const float* feats  = (const float*)d_in[1];
  const float* W      = (const float*)d_in[2];
  const float* bns    = (const float*)d_in[3];
  const float* bnb    = (const float*)d_in[4];
  const float* bnm    = (const float*)d_in[5];
  const float* bnv    = (const float*)d_in[6];
  float* out = (float*)d_out;

  char* ws = (char*)d_ws;
  size_t off = 0;
  auto alloc = [&](size_t bytes) -> void* {
    void* p = ws + off;
    off += (bytes + 255) & ~(size_t)255;
    return p;
  };
  u32* lut      = (u32*)alloc((size_t)NKEYS * 4);        // counts, then rank|flag
  u32* partials = (u32*)alloc((NPART + 8) * 4);
  int* keys     = (int*)alloc((size_t)NPTS * 4);
  int* r2k      = (int*)alloc((size_t)NPTS * 4);
  u16* fdsb     = (u16*)alloc((size_t)NPTS * 64 * 2);
  u16* Wt       = (u16*)alloc((size_t)27 * 4096 * 2);
  float* ab     = (float*)alloc(128 * 4);
  (void)ws_size; (void)out_size; (void)n_in; (void)in_sizes;

  float* fds32 = out;   // d_out doubles as f32 staging for multi-point voxels

  hipMemsetAsync(lut, 0, (size_t)NKEYS * 4, stream);

  k0a_bn<<<1, 64, 0, stream>>>(bns, bnb, bnm, bnv, ab);
  k0b_wt<<<(27 * 4096 + 255) / 256, 256, 0, stream>>>(W, Wt);
  k1_keys<<<(NPTS + 255) / 256, 256, 0, stream>>>(coords, keys, lut);
  k2a_part<<<NPART, 256, 0, stream>>>(lut, partials);
  k2b_top<<<1, NPART, 0, stream>>>(partials);
  k2c_fill<<<NPART, 256, 0, stream>>>(lut, partials, r2k, fds32);
  k3_seg<<<(NPTS * 16 + 255) / 256, 256, 0, stream>>>(feats, keys, lut, fds32, fdsb);
  k3b_fix<<<(NPTS * 4 + 255) / 256, 256, 0, stream>>>(r2k, lut, partials + NPART, fds32, fdsb);
  k4_conv<<<(NPTS + 255) / 256, 256, 0, stream>>>(lut, r2k, fdsb, Wt,
                                                  partials + NPART, ab, out);
}